// Round 1
// baseline (413.645 us; speedup 1.0000x reference)
//
#include <hip/hip_runtime.h>

// out[i,j] = (2*x[i,j] + 3) / (i + 1), x: 8192x8192 fp32.
// Memory-bound: 512 MiB total traffic -> ~85 us at 6.3 TB/s achievable.
// One float4 per thread; row = (vec_idx*4) >> 13 (ncols = 8192 = 2^13,
// divisible by 4, so each float4 is within a single row).

__global__ __launch_bounds__(256) void rowdiv_kernel(const float4* __restrict__ x,
                                                     float4* __restrict__ out) {
    const unsigned int v = blockIdx.x * blockDim.x + threadIdx.x; // float4 index
    const unsigned int row = v >> 11;           // (v*4) >> 13
    const float inv = 1.0f / (float)(row + 1);  // exact divide, then 1 mul each

    float4 a = x[v];
    float4 r;
    r.x = (2.0f * a.x + 3.0f) * inv;
    r.y = (2.0f * a.y + 3.0f) * inv;
    r.z = (2.0f * a.z + 3.0f) * inv;
    r.w = (2.0f * a.w + 3.0f) * inv;
    out[v] = r;
}

extern "C" void kernel_launch(void* const* d_in, const int* in_sizes, int n_in,
                              void* d_out, int out_size, void* d_ws, size_t ws_size,
                              hipStream_t stream) {
    const float4* x = (const float4*)d_in[0];
    float4* out = (float4*)d_out;
    // 8192*8192 = 67,108,864 elements = 16,777,216 float4s
    const unsigned int n_vec4 = 8192u * 8192u / 4u;
    const unsigned int block = 256;
    const unsigned int grid = n_vec4 / block; // 65536
    rowdiv_kernel<<<grid, block, 0, stream>>>(x, out);
}